// Round 5
// baseline (930.160 us; speedup 1.0000x reference)
//
#include <hip/hip_runtime.h>
#include <hip/hip_bf16.h>
#include <cstdint>

// Problem constants: B=4, L=1024, D=1024, H=16, HD=64, FF=4096, NS=64
// Inputs: fp32 (per reference setup_inputs). Output: fp32 (reference returns float32).
#define DEVI __device__ __forceinline__

typedef __attribute__((ext_vector_type(8))) short  short8;
typedef __attribute__((ext_vector_type(8))) __bf16 bf16x8;
typedef __attribute__((ext_vector_type(4))) float  f32x4;

DEVI float bf2f(short s) {
    unsigned u = ((unsigned)(unsigned short)s) << 16;
    return __builtin_bit_cast(float, u);
}
DEVI short f2bf(float f) {
    unsigned u = __builtin_bit_cast(unsigned, f);
    u = u + 0x7FFF + ((u >> 16) & 1);   // RNE
    return (short)(u >> 16);
}

#define GLDS(gp, lp) __builtin_amdgcn_global_load_lds( \
    (const __attribute__((address_space(1))) void*)(gp), \
    (__attribute__((address_space(3))) void*)(lp), 16, 0, 0)

template<int N> DEVI void waitcnt_vm() {
    if constexpr (N == 0)      asm volatile("s_waitcnt vmcnt(0)" ::: "memory");
    else if constexpr (N == 4) asm volatile("s_waitcnt vmcnt(4)" ::: "memory");
    else if constexpr (N == 6) asm volatile("s_waitcnt vmcnt(6)" ::: "memory");
    else if constexpr (N == 8) asm volatile("s_waitcnt vmcnt(8)" ::: "memory");
}

// ---------------------------------------------------- fp32 -> bf16 convert
__global__ __launch_bounds__(256) void cvt_bf16(const float* src, short* dst, long n) {
    const long i = ((long)blockIdx.x * 256 + threadIdx.x) * 8;
    const float4 a = *(const float4*)&src[i];
    const float4 b = *(const float4*)&src[i + 4];
    short8 o;
    o[0] = f2bf(a.x); o[1] = f2bf(a.y); o[2] = f2bf(a.z); o[3] = f2bf(a.w);
    o[4] = f2bf(b.x); o[5] = f2bf(b.y); o[6] = f2bf(b.z); o[7] = f2bf(b.w);
    *(short8*)&dst[i] = o;
}

// All weight conversions in one launch. blkStart is a prefix-sum of per-segment blocks.
struct CvtArgs {
    const float* src[6]; short* dst[6]; int blkStart[7];
};
__global__ __launch_bounds__(256) void cvt_all(CvtArgs c) {
    const int b = blockIdx.x;
    int s = 0;
    while (b >= c.blkStart[s + 1]) s++;
    const long i = ((long)(b - c.blkStart[s]) * 256 + threadIdx.x) * 8;
    const float4 a0 = *(const float4*)&c.src[s][i];
    const float4 a1 = *(const float4*)&c.src[s][i + 4];
    short8 o;
    o[0] = f2bf(a0.x); o[1] = f2bf(a0.y); o[2] = f2bf(a0.z); o[3] = f2bf(a0.w);
    o[4] = f2bf(a1.x); o[5] = f2bf(a1.y); o[6] = f2bf(a1.z); o[7] = f2bf(a1.w);
    *(short8*)&c.dst[s][i] = o;
}

// ---------------------------------------------------------------- GEMM (NT)
// C[m,n] = sum_k A[m,k] * B[n,k]  -- A,B bf16 K-contiguous, fp32 accum.
// 3-buffer, 2-ahead counted-vmcnt pipeline (T3/T4): stage(t+2) -> vmcnt(2*LPS)
// (drains only stage(t); t+1,t+2 stay in flight) -> barrier -> compute(t) -> barrier.
struct GArgs {
    const short* A; long lda, sAb, sAh;
    const short* B; long ldb, sBb, sBh;
    short* C;       long ldc, sCb, sCh;
    const float* bias;                       // len-N fp32, nullable
    const float* addm; long ldad, sDb, sDh;  // additive fp32 matrix (alibi), nullable
    float* resid;                            // fp32 residual, uses ldc
    float* outf;                             // EPI3 fp32 output
    const float* gate;                       // fp32 scalar, nullable
    const float* addf;                       // EPI2: fp32 base matrix (else resid is base)
    float scale;
    int K, nh;
};

// EPI: 0: C=bf16(acc+bias)
//      1: C=bf16(acc*scale + addm)
//      2: resid = (addf?addf:resid) + gatescale*(acc+bias)   (gatescale = scale*sigmoid(*gate))
//      3: outf = fp32(resid + acc + bias)
template<int BM, int BN, int EPI>
__global__ __launch_bounds__(256) void gemm_bt(GArgs a) {
    constexpr int WM = BM / 2, WN = BN / 2, MI = WM / 16, NI = WN / 16;
    constexpr int LPS = BM / 64 + BN / 64;     // per-thread global_load_lds per stage
    __shared__ __align__(16) short As[3][BM * 32];
    __shared__ __align__(16) short Bs[3][BN * 32];
    const int tid = threadIdx.x;
    const int wave = tid >> 6, lane = tid & 63;
    const int wm = (wave >> 1) * WM, wn = (wave & 1) * WN;
    const int q = lane >> 4, r = lane & 15;
    // XCD-aware bijective swizzle over (x,y); requires gx*gy % 8 == 0 (all call sites comply)
    const int gx = gridDim.x, gy = gridDim.y;
    int flat = (int)(blockIdx.y * gx + blockIdx.x);
    { const int cp = (gx * gy) >> 3; flat = (flat & 7) * cp + (flat >> 3); }
    const int bx = flat % gx, by = flat / gx;
    const long bb = blockIdx.z / a.nh, hh = blockIdx.z % a.nh;
    const short* Ab = a.A + bb * a.sAb + hh * a.sAh + (long)by * BM * a.lda;
    const short* Bb = a.B + bb * a.sBb + hh * a.sBh + (long)bx * BN * a.ldb;
    const int trow = tid >> 2;            // 4 threads/row, 8 bf16 (16B) each
    const int tcol = (tid & 3) * 8;
    f32x4 acc[MI][NI] = {};
    const int nt = a.K >> 5;

    auto stage = [&](int buf, int k0) {
#pragma unroll
        for (int i = 0; i < BM / 64; i++)
            GLDS(Ab + (long)(i * 64 + trow) * a.lda + k0 + tcol,
                 &As[buf][(i * 64 + trow) * 32 + tcol]);
#pragma unroll
        for (int i = 0; i < BN / 64; i++)
            GLDS(Bb + (long)(i * 64 + trow) * a.ldb + k0 + tcol,
                 &Bs[buf][(i * 64 + trow) * 32 + tcol]);
    };

    // prologue: fill pipeline 2 deep (nt >= 2 at every call site)
    stage(0, 0);
    stage(1, 32);

    for (int t = 0; t < nt; ++t) {
        const int kn = (t + 2 < nt ? t + 2 : nt - 1) << 5;   // clamp: redundant tail loads
        stage((t + 2) % 3, kn);
        waitcnt_vm<2 * LPS>();          // stage(t) landed; t+1,t+2 in flight
        __builtin_amdgcn_s_barrier();
        const int cur = t % 3;
        bf16x8 av[MI], bv[NI];
#pragma unroll
        for (int mi = 0; mi < MI; mi++)
            av[mi] = __builtin_bit_cast(bf16x8, *(const short8*)&As[cur][(wm + mi * 16 + r) * 32 + q * 8]);
#pragma unroll
        for (int ni = 0; ni < NI; ni++)
            bv[ni] = __builtin_bit_cast(bf16x8, *(const short8*)&Bs[cur][(wn + ni * 16 + r) * 32 + q * 8]);
#pragma unroll
        for (int mi = 0; mi < MI; mi++)
#pragma unroll
            for (int ni = 0; ni < NI; ni++)
                acc[mi][ni] = __builtin_amdgcn_mfma_f32_16x16x32_bf16(av[mi], bv[ni], acc[mi][ni], 0, 0, 0);
        __builtin_amdgcn_s_barrier();   // all reads of buf[cur] done before it is restaged
    }

    const long m0 = (long)by * BM + wm;
    const long n0 = (long)bx * BN + wn;
    float gs = a.scale;
    if (EPI == 2 && a.gate) gs *= 1.f / (1.f + __expf(-(*a.gate)));
#pragma unroll
    for (int mi = 0; mi < MI; mi++)
#pragma unroll
        for (int ni = 0; ni < NI; ni++)
#pragma unroll
            for (int j = 0; j < 4; j++) {
                const long m = m0 + mi * 16 + q * 4 + j;   // row = quad*4+reg
                const long n = n0 + ni * 16 + r;           // col = lane&15
                float v = acc[mi][ni][j];
                if constexpr (EPI == 0) {
                    if (a.bias) v += a.bias[n];
                    a.C[bb * a.sCb + hh * a.sCh + m * a.ldc + n] = f2bf(v);
                } else if constexpr (EPI == 1) {
                    v *= a.scale;
                    if (a.addm) v += a.addm[bb * a.sDb + hh * a.sDh + m * a.ldad + n];
                    a.C[bb * a.sCb + hh * a.sCh + m * a.ldc + n] = f2bf(v);
                } else if constexpr (EPI == 2) {
                    if (a.bias) v += a.bias[n];
                    const long idx = m * a.ldc + n;
                    const float base = a.addf ? a.addf[idx] : a.resid[idx];
                    a.resid[idx] = base + gs * v;
                } else {
                    if (a.bias) v += a.bias[n];
                    a.outf[m * a.ldc + n] = a.resid[m * a.ldc + n] + v;
                }
            }
}

// ------------------------------------------------- fused GEMM + GeGLU (3-buf pipeline)
// C[m,n] = bf16( (A·Bv^T + b1[n]) * gelu(A·Bg^T + b1[4096+n]) )
struct GGArgs {
    const short* A; long lda;
    const short* Bv; const short* Bg; long ldb;
    short* C; long ldc;
    const float* b1;     // len 8192
    int K;
};
__global__ __launch_bounds__(256) void gemm_geglu(GGArgs a) {
    constexpr int BM = 128, BN = 64, WM = 64, WN = 32, MI = 4, NI = 2;
    __shared__ __align__(16) short As[3][BM * 32];
    __shared__ __align__(16) short Bs[3][BN * 32];
    __shared__ __align__(16) short Gs[3][BN * 32];
    const int tid = threadIdx.x;
    const int wave = tid >> 6, lane = tid & 63;
    const int wm = (wave >> 1) * WM, wn = (wave & 1) * WN;
    const int q = lane >> 4, r = lane & 15;
    const int gx = gridDim.x, gy = gridDim.y;
    int flat = (int)(blockIdx.y * gx + blockIdx.x);
    { const int cp = (gx * gy) >> 3; flat = (flat & 7) * cp + (flat >> 3); }
    const int bx = flat % gx, by = flat / gx;
    const short* Ab = a.A + (long)by * BM * a.lda;
    const short* Bb = a.Bv + (long)bx * BN * a.ldb;
    const short* Gb = a.Bg + (long)bx * BN * a.ldb;
    const int trow = tid >> 2, tcol = (tid & 3) * 8;
    f32x4 accv[MI][NI] = {}, accg[MI][NI] = {};
    const int nt = a.K >> 5;

    auto stage = [&](int buf, int k0) {
#pragma unroll
        for (int i = 0; i < 2; i++)
            GLDS(Ab + (long)(i * 64 + trow) * a.lda + k0 + tcol,
                 &As[buf][(i * 64 + trow) * 32 + tcol]);
        GLDS(Bb + (long)trow * a.ldb + k0 + tcol, &Bs[buf][trow * 32 + tcol]);
        GLDS(Gb + (long)trow * a.ldb + k0 + tcol, &Gs[buf][trow * 32 + tcol]);
    };

    stage(0, 0);
    stage(1, 32);

    for (int t = 0; t < nt; ++t) {
        const int kn = (t + 2 < nt ? t + 2 : nt - 1) << 5;
        stage((t + 2) % 3, kn);
        waitcnt_vm<8>();                // 2 stages x 4 loads in flight
        __builtin_amdgcn_s_barrier();
        const int cur = t % 3;
        bf16x8 av[MI], bv[NI], gv[NI];
#pragma unroll
        for (int mi = 0; mi < MI; mi++)
            av[mi] = __builtin_bit_cast(bf16x8, *(const short8*)&As[cur][(wm + mi * 16 + r) * 32 + q * 8]);
#pragma unroll
        for (int ni = 0; ni < NI; ni++) {
            bv[ni] = __builtin_bit_cast(bf16x8, *(const short8*)&Bs[cur][(wn + ni * 16 + r) * 32 + q * 8]);
            gv[ni] = __builtin_bit_cast(bf16x8, *(const short8*)&Gs[cur][(wn + ni * 16 + r) * 32 + q * 8]);
        }
#pragma unroll
        for (int mi = 0; mi < MI; mi++)
#pragma unroll
            for (int ni = 0; ni < NI; ni++) {
                accv[mi][ni] = __builtin_amdgcn_mfma_f32_16x16x32_bf16(av[mi], bv[ni], accv[mi][ni], 0, 0, 0);
                accg[mi][ni] = __builtin_amdgcn_mfma_f32_16x16x32_bf16(av[mi], gv[ni], accg[mi][ni], 0, 0, 0);
            }
        __builtin_amdgcn_s_barrier();
    }

    const long m0 = (long)by * BM + wm;
    const long n0 = (long)bx * BN + wn;
#pragma unroll
    for (int mi = 0; mi < MI; mi++)
#pragma unroll
        for (int ni = 0; ni < NI; ni++)
#pragma unroll
            for (int j = 0; j < 4; j++) {
                const long m = m0 + mi * 16 + q * 4 + j;
                const long n = n0 + ni * 16 + r;
                const float v = accv[mi][ni][j] + a.b1[n];
                const float g = accg[mi][ni][j] + a.b1[4096 + n];
                const float ge = 0.5f * g * (1.f + erff(g * 0.7071067811865476f));
                a.C[m * a.ldc + n] = f2bf(v * ge);
            }
}

// ------------------------------------------------- flash self-attention
// grid: (16 q-tiles, 64 bh). Block 256 = 4 waves; wave w owns rows [w*16,w*16+16).
// Q in registers; K/V/alibi double-buffered in LDS; 1-ahead counted vmcnt(8).
// Alibi tile staged via global_load_lds with chunk-XOR swizzle (c ^ ((row>>2)&3))
// so the 4 q-quads reading the same column land in different banks.
__global__ __launch_bounds__(256) void flash_sa(const short* qkv, const short* vt,
                                                const float* alibi, short* Obuf) {
    __shared__ __align__(16) short Ps[64 * 64];          // Q staging, then P tiles
    __shared__ __align__(16) short Ks[2][64 * 64], Vs[2][64 * 64];
    __shared__ __align__(16) float Al[2][64 * 64];
    const int tid = threadIdx.x;
    const int wave = tid >> 6, lane = tid & 63, q = lane >> 4, r = lane & 15;
    int flat = (int)(blockIdx.y * 16 + blockIdx.x);     // nwg = 1024
    flat = (flat & 7) * 128 + (flat >> 3);              // XCD chunk swizzle
    const int qt = flat & 15, bh = flat >> 4, b = bh >> 4, h = bh & 15;
    const long qrow0 = (long)b * 1024 + qt * 64;
    const int rw = tid >> 3, sp = tid & 7;   // bf16 loader: 8 threads/row, 16B each
    const float* alb = alibi + (long)bh * 1048576 + (long)(qt * 64) * 1024;

    auto stage_kva = [&](int buf, int kt) {
#pragma unroll
        for (int i = 0; i < 2; i++) {
            const int row = i * 32 + rw;
            const int c8 = (sp ^ (row & 7)) * 8;
            GLDS(qkv + ((long)b * 1024 + kt * 64 + row) * 3072 + 1024 + h * 64 + c8,
                 &Ks[buf][row * 64 + sp * 8]);
            GLDS(vt + ((long)bh * 64 + row) * 1024 + kt * 64 + c8,
                 &Vs[buf][row * 64 + sp * 8]);
        }
        // alibi: 64x64 fp32 tile, 16B chunks; dest linear, source chunk-swizzled
#pragma unroll
        for (int i = 0; i < 4; i++) {
            const int f = i * 256 + tid;            // chunk index 0..1023
            const int arow = f >> 4, cdst = f & 15;
            const int csrc = cdst ^ ((arow >> 2) & 3);
            GLDS(alb + (long)arow * 1024 + kt * 64 + csrc * 4,
                 &Al[buf][arow * 64 + cdst * 4]);
        }
    };

    // stage Q (into Ps) + K/V/alibi tile 0
#pragma unroll
    for (int i = 0; i < 2; i++) {
        const int row = i * 32 + rw;
        const int c8 = (sp ^ (row & 7)) * 8;
        GLDS(qkv + (qrow0 + row) * 3072 + h * 64 + c8, &Ps[row * 64 + sp * 8]);
    }
    stage_kva(0, 0);
    waitcnt_vm<0>();
    __builtin_amdgcn_s_barrier();

    // Q-hoist: each wave reads only its own 16-row strip (rows wave*16 + r)
    const int arow = wave * 16 + r;
    bf16x8 qv[2];
#pragma unroll
    for (int kk = 0; kk < 2; kk++)
        qv[kk] = __builtin_bit_cast(bf16x8,
            *(const short8*)&Ps[arow * 64 + (((kk * 4 + q) ^ (arow & 7)) * 8)]);
    // (no barrier: each wave overwrites only its own strip of Ps below)

    f32x4 o[4] = {};            // O accum: row q*4+j, col d = nd*16+r
    float m_run[4], l_run[4];
#pragma unroll
    for (int j = 0; j < 4; j++) { m_run[j] = -1e30f; l_run[j] = 0.f; }

    int cur = 0;
    for (int kt = 0; kt < 16; kt++) {
        stage_kva(cur ^ 1, kt < 15 ? kt + 1 : 15);   // clamp: final iter redundant
        waitcnt_vm<8>();         // stage(kt) landed; stage(kt+1)'s 8 loads in flight
        __builtin_amdgcn_s_barrier();

        // S = Q K^T  (wave strip: 16 rows x 64 cols) from Ks[cur]
        f32x4 sacc[4] = {};
#pragma unroll
        for (int kk = 0; kk < 2; kk++) {
#pragma unroll
            for (int ni = 0; ni < 4; ni++) {
                const int brow = ni * 16 + r;
                const bf16x8 bv = __builtin_bit_cast(bf16x8,
                    *(const short8*)&Ks[cur][brow * 64 + (((kk * 4 + q) ^ (brow & 7)) * 8)]);
                sacc[ni] = __builtin_amdgcn_mfma_f32_16x16x32_bf16(qv[kk], bv, sacc[ni], 0, 0, 0);
            }
        }
        // s = S/8 + alibi (alibi from LDS; logical (row,col) at chunk c^q)
        float s[4][4];
#pragma unroll
        for (int ni = 0; ni < 4; ni++) {
            const int cl = ni * 4 + (r >> 2);
#pragma unroll
            for (int j = 0; j < 4; j++) {
                const float alv = Al[cur][(wave * 16 + q * 4 + j) * 64 + ((cl ^ q) << 2) + (r & 3)];
                s[ni][j] = sacc[ni][j] * 0.125f + alv;
            }
        }

        // online softmax: row = q*4+j, owned by the 16 lanes sharing q
        float p[4][4];
#pragma unroll
        for (int j = 0; j < 4; j++) {
            float mx = fmaxf(fmaxf(s[0][j], s[1][j]), fmaxf(s[2][j], s[3][j]));
#pragma unroll
            for (int off = 8; off; off >>= 1) mx = fmaxf(mx, __shfl_xor(mx, off));
            const float newm = fmaxf(m_run[j], mx);
            const float sc = __expf(m_run[j] - newm);
            m_run[j] = newm;
            float rs = 0.f;
#pragma unroll
            for (int ni = 0; ni < 4; ni++) { p[ni][j] = __expf(s[ni][j] - newm); rs += p[ni][j]; }
#pragma unroll
            for (int off = 8; off; off >>= 1) rs += __shfl_xor(rs, off);
            l_run[j] = l_run[j] * sc + rs;
#pragma unroll
            for (int nd = 0; nd < 4; nd++) o[nd][j] *= sc;
        }

        // P -> bf16 -> LDS (own strip only; swizzled elementwise)
#pragma unroll
        for (int ni = 0; ni < 4; ni++)
#pragma unroll
            for (int j = 0; j < 4; j++) {
                const int row = wave * 16 + q * 4 + j;
                const int col = ni * 16 + r;
                const int scol = (((col >> 3) ^ (row & 7)) << 3) | (col & 7);
                Ps[row * 64 + scol] = f2bf(p[ni][j]);
            }
        asm volatile("s_waitcnt lgkmcnt(0)" ::: "memory");   // within-wave write->read

        // O += P @ V from Vs[cur]
        const int prow = wave * 16 + r;
#pragma unroll
        for (int kk = 0; kk < 2; kk++) {
            const bf16x8 pa = __builtin_bit_cast(bf16x8,
                *(const short8*)&Ps[prow * 64 + (((kk * 4 + q) ^ (prow & 7)) * 8)]);
#pragma unroll
            for (int nd = 0; nd < 4; nd++) {
                const int vrow = nd * 16 + r;
                const bf16x8 vv = __builtin_bit_cast(bf16x8,
                    *(const short8*)&Vs[cur][vrow * 64 + (((kk * 4 + q) ^ (vrow & 7)) * 8)]);
                o[nd] = __builtin_amdgcn_mfma_f32_16x16x32_bf16(pa, vv, o[nd], 0, 0, 0);
            }
        }
        __builtin_amdgcn_s_barrier();   // buf[cur] reads done before next restage
        cur ^= 1;
    }

    // epilogue: O /= l, write bf16
#pragma unroll
    for (int nd = 0; nd < 4; nd++)
#pragma unroll
        for (int j = 0; j < 4; j++) {
            const long m = qrow0 + wave * 16 + q * 4 + j;
            Obuf[m * 1024 + h * 64 + nd * 16 + r] = f2bf(o[nd][j] / l_run[j]);
        }
}

// ------------------------------------------------- flash cross-attention
// Single KV tile (NS=64): S = Q2 K2^T / 8, softmax, O = P V2. grid (16, 64).
__global__ __launch_bounds__(256) void flash_ca(const short* q2, const short* kv2,
                                                const short* vt, short* Obuf) {
    __shared__ __align__(16) short Qs[64 * 64], Ks[64 * 64], Vs[64 * 64], Ps[64 * 64];
    const int tid = threadIdx.x;
    const int wave = tid >> 6, lane = tid & 63, q = lane >> 4, r = lane & 15;
    int flat = (int)(blockIdx.y * 16 + blockIdx.x);
    flat = (flat & 7) * 128 + (flat >> 3);
    const int qt = flat & 15, bh = flat >> 4, b = bh >> 4, h = bh & 15;
    const long qrow0 = (long)b * 1024 + qt * 64;
    const int rw = tid >> 3, sp = tid & 7;

#pragma unroll
    for (int i = 0; i < 2; i++) {
        const int row = i * 32 + rw;
        const int c8 = (sp ^ (row & 7)) * 8;
        GLDS(q2 + (qrow0 + row) * 1024 + h * 64 + c8, &Qs[row * 64 + sp * 8]);
        GLDS(kv2 + ((long)b * 64 + row) * 2048 + h * 64 + c8, &Ks[row * 64 + sp * 8]);
        GLDS(vt + ((long)bh * 64 + row) * 64 + c8, &Vs[row * 64 + sp * 8]);
    }
    waitcnt_vm<0>();
    __syncthreads();

    // S = Q K^T / 8
    f32x4 sacc[4] = {};
    const int arow = wave * 16 + r;
#pragma unroll
    for (int kk = 0; kk < 2; kk++) {
        const bf16x8 av = __builtin_bit_cast(bf16x8,
            *(const short8*)&Qs[arow * 64 + (((kk * 4 + q) ^ (arow & 7)) * 8)]);
#pragma unroll
        for (int ni = 0; ni < 4; ni++) {
            const int brow = ni * 16 + r;
            const bf16x8 bv = __builtin_bit_cast(bf16x8,
                *(const short8*)&Ks[brow * 64 + (((kk * 4 + q) ^ (brow & 7)) * 8)]);
            sacc[ni] = __builtin_amdgcn_mfma_f32_16x16x32_bf16(av, bv, sacc[ni], 0, 0, 0);
        }
    }
    // softmax over the full 64 keys
    float p[4][4], linv[4];
#pragma unroll
    for (int j = 0; j < 4; j++) {
        float s0 = sacc[0][j] * 0.125f, s1 = sacc[1][j] * 0.125f;
        float s2 = sacc[2][j] * 0.125f, s3 = sacc[3][j] * 0.125f;
        float mx = fmaxf(fmaxf(s0, s1), fmaxf(s2, s3));
#pragma unroll
        for (int off = 8; off; off >>= 1) mx = fmaxf(mx, __shfl_xor(mx, off));
        p[0][j] = __expf(s0 - mx); p[1][j] = __expf(s1 - mx);
        p[2][j] = __expf(s2 - mx); p[3][j] = __expf(s3 - mx);
        float rs = p[0][j] + p[1][j] + p[2][j] + p[3][j];
#pragma unroll
        for (int off = 8; off; off >>= 1) rs += __shfl_xor(rs, off);
        linv[j] = 1.f / rs;
    }
#pragma unroll
    for (int ni = 0; ni < 4; ni++)
#pragma unroll
        for (int j = 0; j < 4; j++) {
            const int row = wave * 16 + q * 4 + j;
            const int col = ni * 16 + r;
            const int scol = (((col >> 3) ^ (row & 7)) << 3) | (col & 7);
            Ps[row * 64 + scol] = f2bf(p[ni][j]);
        }
    asm volatile("s_waitcnt lgkmcnt(0)" ::: "memory");

    f32x4 o[4] = {};
    const int prow = wave * 16 + r;
#pragma unroll
    for (int kk = 0; kk < 2; kk++) {
        const bf16x8 pa = __builtin_bit_cast(bf16x8,
            *(const short8*)&Ps[prow * 64 + (((kk * 4 + q) ^ (prow & 7)) * 8)]);
#pragma unroll
        for (int nd = 0; nd < 4; nd++) {
            const int vrow = nd * 16 + r;
            const bf16x8 vv = __builtin_bit_cast(bf16x8,
                *(const short8*)&Vs[vrow * 64 + (((kk * 4 + q) ^ (vrow & 7)) * 8)]);
            o[nd] = __builtin_amdgcn_mfma_f32_16x16x32_bf16(pa, vv, o[nd], 0, 0, 0);
        }
    }
#pragma unroll
    for (int nd = 0; nd < 4; nd++)
#pragma unroll
        for (int j = 0; j < 4; j++) {
            const long m = qrow0 + wave * 16 + q * 4 + j;
            Obuf[m * 1024 + h * 64 + nd * 16 + r] = f2bf(o[nd][j] * linv[j]);
        }
}

// ------------------------------------------------------------- LayerNorm
__global__ __launch_bounds__(256) void ln_rows(const float* X, const float* gw,
                                               const float* bw, short* Y) {
    const long row = blockIdx.x;
    const float* x = X + row * 1024;
    const int t = threadIdx.x;
    float v[4], s1 = 0.f, s2 = 0.f;
#pragma unroll
    for (int i = 0; i < 4; i++) {
        v[i] = x[t + i * 256];
        s1 += v[i]; s2 += v[i] * v[i];
    }
#pragma unroll
    for (int o = 32; o; o >>= 1) { s1 += __shfl_xor(s1, o); s2 += __shfl_xor(s2, o); }
    __shared__ float sm[8];
    if ((t & 63) == 0) { sm[t >> 6] = s1; sm[4 + (t >> 6)] = s2; }
    __syncthreads();
    s1 = sm[0] + sm[1] + sm[2] + sm[3];
    s2 = sm[4] + sm[5] + sm[6] + sm[7];
    const float mu = s1 * (1.f / 1024.f);
    const float var = s2 * (1.f / 1024.f) - mu * mu;
    const float rr = rsqrtf(var + 1e-5f);
#pragma unroll
    for (int i = 0; i < 4; i++) {
        const int c = t + i * 256;
        Y[row * 1024 + c] = f2bf((v[i] - mu) * rr * gw[c] + bw[c]);
    }
}

// ------------------------------------------------------------- Softmax (fallback path)
__global__ __launch_bounds__(256) void softmax1024(short* S) {
    const long row = blockIdx.x;
    short* p = S + row * 1024;
    const int t = threadIdx.x;
    float v[4];
#pragma unroll
    for (int i = 0; i < 4; i++) v[i] = bf2f(p[t + i * 256]);
    float m = fmaxf(fmaxf(v[0], v[1]), fmaxf(v[2], v[3]));
#pragma unroll
    for (int o = 32; o; o >>= 1) m = fmaxf(m, __shfl_xor(m, o));
    __shared__ float sm[4];
    if ((t & 63) == 0) sm[t >> 6] = m;
    __syncthreads();
    m = fmaxf(fmaxf(sm[0], sm[1]), fmaxf(sm[2], sm[3]));
    float e[4], s = 0.f;
#pragma unroll
    for (int i = 0; i < 4; i++) { e[i] = __expf(v[i] - m); s += e[i]; }
#pragma unroll
    for (int o = 32; o; o >>= 1) s += __shfl_xor(s, o);
    __syncthreads();
    if ((t & 63) == 0) sm[t >> 6] = s;
    __syncthreads();
    s = sm[0] + sm[1] + sm[2] + sm[3];
    const float inv = 1.f / s;
#pragma unroll
    for (int i = 0; i < 4; i++) p[t + i * 256] = f2bf(e[i] * inv);
}

__global__ __launch_bounds__(256) void softmax64(short* S) {
    const long row = (long)blockIdx.x * 4 + (threadIdx.x >> 6);
    const int lane = threadIdx.x & 63;
    short* p = S + row * 64;
    float v = bf2f(p[lane]);
    float m = v;
#pragma unroll
    for (int o = 32; o; o >>= 1) m = fmaxf(m, __shfl_xor(m, o));
    float e = __expf(v - m), s = e;
#pragma unroll
    for (int o = 32; o; o >>= 1) s += __shfl_xor(s, o);
    p[lane] = f2bf(e / s);
}

// ----------------------------------------------------- V transposes (per head)
__global__ __launch_bounds__(256) void transpose_v_sa(const short* qkv, short* vt) {
    __shared__ short tbuf[64][68];
    const int j0 = blockIdx.x * 64, h = blockIdx.y, b = blockIdx.z;
    const int tid = threadIdx.x;
#pragma unroll
    for (int i = 0; i < 16; i++) {
        const int idx = i * 256 + tid, jj = idx >> 6, hd = idx & 63;
        tbuf[jj][hd] = qkv[(long)(b * 1024 + j0 + jj) * 3072 + 2048 + h * 64 + hd];
    }
    __syncthreads();
    const long bh = b * 16 + h;
#pragma unroll
    for (int i = 0; i < 16; i++) {
        const int idx = i * 256 + tid, hd = idx >> 6, jj = idx & 63;
        vt[(bh * 64 + hd) * 1024 + j0 + jj] = tbuf[jj][hd];
    }
}

__global__ __launch_bounds__(256) void transpose_v_ca(const short* kv2, short* vt2) {
    __shared__ short tbuf[64][68];
    const int bh = blockIdx.x, b = bh >> 4, h = bh & 15;
    const int tid = threadIdx.x;
#pragma unroll
    for (int i = 0; i < 16; i++) {
        const int idx = i * 256 + tid, jj = idx >> 6, hd = idx & 63;
        tbuf[jj][hd] = kv2[(long)(b * 64 + jj) * 2048 + 1024 + h * 64 + hd];
    }
    __syncthreads();
#pragma unroll
    for (int i = 0; i < 16; i++) {
        const int idx = i * 256 + tid, hd = idx >> 6, jj = idx & 63;
        vt2[((long)bh * 64 + hd) * 64 + jj] = tbuf[jj][hd];
    }
}

// ------------------------------------------------------------- elementwise (fallback)
__global__ __launch_bounds__(256) void geglu_inplace(short* f1) {
    const long i = (long)blockIdx.x * 256 + threadIdx.x;  // 8 elems each
    const long m = i >> 9, j8 = (i & 511) * 8;
    const short8 av = *(const short8*)&f1[m * 8192 + j8];
    const short8 gv = *(const short8*)&f1[m * 8192 + 4096 + j8];
    short8 o;
#pragma unroll
    for (int jj = 0; jj < 8; jj++) {
        const float xv = bf2f(av[jj]), gg = bf2f(gv[jj]);
        const float ge = 0.5f * gg * (1.f + erff(gg * 0.7071067811865476f));
        o[jj] = f2bf(xv * ge);
    }
    *(short8*)&f1[m * 8192 + j8] = o;
}

// ---------------------------------------------------------------- launch
extern "C" void kernel_launch(void* const* d_in, const int* in_sizes, int n_in,
                              void* d_out, int out_size, void* d_ws, size_t ws_size,
                              hipStream_t stream) {
    const float* x        = (const float*)d_in[0];
    const float* alibi    = (const float*)d_in[1];
    const float* species  = (const float*)d_in[2];
    const float* n1g      = (const float*)d_in[3];
    const float* n1b      = (const float*)d_in[4];
    const float* sa_wqkv  = (const float*)d_in[5];
    const float* sa_bqkv  = (const float*)d_in[6];
    const float* sa_wo    = (const float*)d_in[7];
    const float* sa_bo    = (const float*)d_in[8];
    const float* ca_nq_g  = (const float*)d_in[9];
    const float* ca_nq_b  = (const float*)d_in[10];
    const float* ca_nkv_g = (const float*)d_in[11];
    const float* ca_nkv_b = (const float*)d_in[12];
    const float* ca_wqkv  = (const float*)d_in[13];
    const float* ca_bqkv  = (const float*)d_in[14];
    const float* ca_wo    = (const float*)d_in[15];
    const float* ca_bo    = (const float*)d_in[16];
    const float* gate     = (const float*)d_in[17];
    const float* ffn_g    = (const float*)d_in[18];
    const float* ffn_b    = (const float*)d_in[19];
    const float* ffn_w1   = (const float*)d_in[20];
    const float* ffn_b1   = (const float*)d_in[21];
    const float* ffn_w2   = (const float*)d_in[22];
    const float* ffn_b2   = (const float*)d_in[23];
    float* out = (float*)d_out;   // fp32 output (reference returns float32)

    const dim3 blk(256);
    char* ws = (char*)d_ws;

    if (ws_size >= (304ull << 20)) {
        // ---------------- de-chunked path (needs 304 MiB workspace) ----------------
        float* resid  = (float*)(ws);                  // [0,16M)    fp32 residual
        short* lnbuf  = (short*)(ws + (16l << 20));    // [16,24M)   LN outputs (bf16)
        short* Obuf   = (short*)(ws + (24l << 20));    // [24,32M)   attn head outputs
        short* vt     = (short*)(ws + (32l << 20));    // [32,40M)   transposed V
        short* qkv    = (short*)(ws + (40l << 20));    // [40,64M)   qkv (4096x3072) / q2
        short* w_saq  = (short*)(ws + (64l << 20));    // [64,70M)
        short* w_sawo = (short*)(ws + (70l << 20));    // [70,72M)
        short* w_caq  = (short*)(ws + (72l << 20));    // [72,78M)
        short* w_cawo = (short*)(ws + (78l << 20));    // [78,80M)
        short* w_f1   = (short*)(ws + (80l << 20));    // [80,96M)
        short* w_f2   = (short*)(ws + (96l << 20));    // [96,104M)
        short* kv2    = (short*)(ws + (104l << 20));   // [104,105M) CA k/v proj (256x2048)
        short* g1     = (short*)(ws + (240l << 20));   // [240,272M) geglu'd f1 (4096x4096)

        // Convert all weights fp32 -> bf16 in one launch
        {
            CvtArgs c{};
            c.src[0] = sa_wqkv; c.dst[0] = w_saq;
            c.src[1] = sa_wo;   c.dst[1] = w_sawo;
            c.src[2] = ca_wqkv; c.dst[2] = w_caq;
            c.src[3] = ca_wo;   c.dst[3] = w_cawo;
            c.src[4] = ffn_w1;  c.dst[4] = w_f1;
            c.src[5] = ffn_w2;  c.dst[5] = w_f2;
            const int nb[6] = {1536, 512, 1536, 512, 4096, 2048};
            int acc = 0;
            for (int i = 0; i < 6; i++) { c.blkStart[i] = acc; acc += nb[i]; }
            c.blkStart[6] = acc;
            cvt_all<<<acc, blk, 0, stream>>>(c);
        }

        // h = LN(x)
        ln_rows<<<4096, blk, 0, stream>>>(x, n1g, n1b, lnbuf);

        // qkv = h @ sa_wqkv^T + b   (4096 x 3072)
        {
            GArgs a{}; a.A = lnbuf; a.lda = 1024; a.B = w_saq; a.ldb = 1024;
            a.C = qkv; a.ldc = 3072; a.bias = sa_bqkv; a.K = 1024; a.nh = 1; a.scale = 1.f;
            gemm_bt<128, 128, 0><<<dim3(24, 32, 1), blk, 0, stream>>>(a);
        }
        transpose_v_sa<<<dim3(16, 16, 4), blk, 0, stream>>>(qkv, vt);

        // fused flash self-attention
        flash_sa<<<dim3(16, 64), blk, 0, stream>>>(qkv, vt, alibi, Obuf);

        {   // resid = x + O @ sa_wo^T + bo   (residual copy folded in)
            GArgs a{}; a.A = Obuf; a.lda = 1024; a.B = w_sawo; a.ldb = 1024;
            a.ldc = 1024; a.bias = sa_bo; a.resid = resid; a.addf = x;
            a.scale = 1.f; a.K = 1024; a.nh = 1;
            gemm_bt<128, 64, 2><<<dim3(16, 32, 1), blk, 0, stream>>>(a);
        }

        // ---- cross attention ----
        ln_rows<<<4096, blk, 0, stream>>>(resid, ca_nq_g, ca_nq_b, lnbuf);
        {   // q2 = LN(x) @ ca_wqkv[0:1024]^T + b
            GArgs a{}; a.A = lnbuf; a.lda = 1024; a.B = w_caq; a.ldb = 1024;
            a.C = qkv; a.ldc = 1024; a.bias = ca_bqkv; a.K = 1024; a.nh = 1; a.scale = 1.f;
            gemm_bt<128, 64, 0><<<dim3(16, 32, 1), blk, 0, stream>>>(a);
        }
        ln_rows<<<256, blk, 0, stream>>>(species, ca_nkv_g, ca_nkv_b, lnbuf);
        {   // kv2 = LN(species) @ ca_wqkv[1024:3072]^T + b   (256 x 2048)
            GArgs a{}; a.A = lnbuf; a.lda = 1024; a.B = w_caq + 1024 * 1024; a.ldb = 1024;
            a.C = kv2; a.ldc = 2048; a.bias = ca_bqkv + 1024; a.K = 1024; a.nh = 1; a.scale = 1.f;
            gemm_bt<128, 128, 0><<<dim3(16, 2, 1), blk, 0, stream>>>(a);
        }
        transpose_v_ca<<<64, blk, 0, stream>>>(kv2, vt);

        // fused flash cross-attention
        flash_ca<<<dim3(16, 64), blk, 0, stream>>>(qkv, kv2, vt, Obuf);

        {   // resid += sigmoid(gate) * (O @ ca_wo^T + bo)
            GArgs a{}; a.A = Obuf; a.lda = 1024; a.B = w_cawo; a.ldb = 1024;
            a.ldc = 1024; a.bias = ca_bo; a.resid = resid; a.gate = gate;
            a.scale = 1.f; a.K = 1024; a.nh = 1;
            gemm_bt<128, 64, 2><<<dim3(16, 32, 1), blk, 0, stream>>>(a);
        }

        // ---- FFN (fused GEMM+GeGLU, then f2) ----
        ln_rows<<<4096, blk, 0, stream>>>(resid, ffn_g, ffn_b, lnbuf);
        {   // g1 = (LN @ w1v^T + b1v) * gelu(LN @ w1g^T + b1g)   (4096 x 4096)
            GGArgs a{}; a.A = lnbuf; a.lda = 1024;
            a.Bv = w_f1; a.Bg = w_f1 + (long)4096 * 1024; a.ldb = 1024;
            a.C = g1; a.ldc = 4096; a.b1 = ffn_b1; a.K = 1024;
            gemm_geglu<<<dim3(64, 32, 1), blk, 0, stream>>>(a);
        }
        {   // out = resid + g1 @ ffn_w2^T + b2
            GArgs a{}; a.A = g1; a.lda = 4096; a.B = w_f2; a.ldb = 4096;
            a.ldc = 1024; a.bias = ffn_b2; a.resid = resid; a.outf = out;
            a.scale = 1.f; a.K = 4096; a.nh = 1;
            gemm_bt<128, 64, 3><<<dim3(16, 32, 1), blk, 0, stream>>>(a);
        }
        return;
    }

    // ---------------- fallback: original 96 MiB chunked path ----------------
    float* resid  = (float*)(ws);                 // [0,16M)   fp32 residual
    short* lnbuf  = (short*)(ws + (16l << 20));   // [16,24M)  LN outputs (bf16)
    short* Obuf   = (short*)(ws + (24l << 20));   // [24,32M)  attn head outputs
    short* vt     = (short*)(ws + (32l << 20));   // [32,40M)  transposed V
    short* qkv    = (short*)(ws + (40l << 20));   // [40,64M)  qkv / q2+kv2; later FFN weights
    short* Sbuf   = (short*)(ws + (64l << 20));   // [64,96M)  scores / f1 chunks
    short* f1     = Sbuf;
    short* kv2    = qkv + 4194304;                // [48,49M)  CA k/v proj (256 x 2048)
    short* w_sawo = (short*)(ws + (80l << 20));   // [80,82M)  sa_wo bf16
    short* w_caq  = (short*)(ws + (82l << 20));   // [82,88M)  ca_wqkv bf16
    short* w_cawo = (short*)(ws + (88l << 20));   // [88,90M)  ca_wo bf16
    short* w_saq  = (short*)(ws + (90l << 20));   // [90,96M)  sa_wqkv bf16 (dead after qkv GEMM)
    short* w_f1   = qkv;                          // [40,56M)  ffn_w1 bf16 (after CA S2)
    short* w_f2   = (short*)(ws + (56l << 20));   // [56,64M)  ffn_w2 bf16

    cvt_bf16<<<1536, blk, 0, stream>>>(sa_wqkv, w_saq, 3145728);
    cvt_bf16<<<512,  blk, 0, stream>>>(sa_wo,   w_sawo, 1048576);
    cvt_bf16<<<1536, blk, 0, stream>>>(ca_wqkv, w_caq, 3145728);
    cvt_bf16<<<512,  blk, 0, stream>>>(ca_wo,   w_cawo, 1048576);

    hipMemcpyAsync(resid, x, (size_t)4194304 * 4, hipMemcpyDeviceToDevice, stream);
    ln_rows<<<4096, blk, 0, stream>>>(x, n1g, n1b, lnbuf);

    {
        GArgs a{}; a.A = lnbuf; a.lda = 1024; a.B = w_saq; a.ldb = 1024;
        a.C = qkv; a.ldc = 3072; a.bias = sa_bqkv; a.K = 1024; a.nh = 1; a.scale = 1.f;
        gemm_bt<128, 128, 0><<<dim3(24, 32, 1), blk, 0, stream>>>(a);
    }
    transpose_v_sa<<<dim3(16, 16, 4), blk, 0, stream>>>(qkv, vt);

    for (int c = 0; c < 8; c++) {
        const int b = c >> 1, hc = c & 1;
        const long boff = (long)b * 1024 * 3072;
        {
            GArgs a{}; a.A = qkv + boff + hc * 512; a.lda = 3072; a.sAh = 64;
            a.B = qkv + boff + 1024 + hc * 512; a.ldb = 3072; a.sBh = 64;
            a.C = Sbuf; a.ldc = 1024; a.sCh = 1048576;
            a.addm = alibi + ((long)(b * 16 + hc * 8)) * 1048576; a.ldad = 1024; a.sDh = 1048576;
            a.scale = 0.125f; a.K = 64; a.nh = 8;
            gemm_bt<128, 128, 1><<<dim3(8, 8, 8), blk, 0, stream>>>(a);
        }
        softmax1024<<<8192, blk, 0, stream>>>(Sbuf);
        {
            GArgs a{}; a.A = Sbuf; a.lda = 1024; a.sAh = 1048576;
            a.B = vt + (long)b * 1048576 + (long)hc * 8 * 65536; a.ldb = 1024; a.sBh = 65536;
            a.C = Obuf + (long)b * 1048576 + hc * 512; a.ldc = 1024; a.sCh = 64;
            a.K = 1024; a.nh = 8; a.scale = 1.f;
            gemm_bt<64, 64, 0><<<dim3(1, 16, 8), blk, 0, stream>>>(a);
        }
    }
    {
        GArgs a{}; a.A = Obuf; a.lda = 1024; a.B = w_sawo; a.ldb = 1024;
        a.ldc = 1024; a.bias = sa_bo; a.resid = resid; a.scale = 1.f; a.K = 1024; a.nh = 1;
        gemm_bt<128, 128, 2><<<dim3(8, 32, 1), blk, 0, stream>>>(a);
    }

    ln_rows<<<4096, blk, 0, stream>>>(resid, ca_nq_g, ca_nq_b, lnbuf);
    {
        GArgs a{}; a.A = lnbuf; a.lda = 1024; a.B = w_caq; a.ldb = 1024;
        a.C = qkv; a.ldc = 1024; a.bias = ca_bqkv; a.K = 1024; a.nh = 1; a.scale = 1.f;
        gemm_bt<128, 128, 0><<<dim3(8, 32, 1), blk, 0, stream>>>(a);
    }
    ln_rows<<<256, blk, 0, stream>>>(species, ca_nkv_g, ca_nkv_b, lnbuf);
    {
        GArgs a{}; a.A = lnbuf; a.lda = 1024; a.B = w_caq + 1024 * 1024; a.ldb = 1024;
        a.C = kv2; a.ldc = 2048; a.bias = ca_bqkv + 1024; a.K = 1024; a.nh = 1; a.scale = 1.f;
        gemm_bt<128, 128, 0><<<dim3(16, 2, 1), blk, 0, stream>>>(a);
    }
    transpose_v_ca<<<64, blk, 0, stream>>>(kv2, vt);
    {
        GArgs a{}; a.A = qkv; a.lda = 1024; a.sAb = 1048576; a.sAh = 64;
        a.B = kv2; a.ldb = 2048; a.sBb = 131072; a.sBh = 64;
        a.C = Sbuf; a.ldc = 64; a.sCb = 1048576; a.sCh = 65536;
        a.scale = 0.125f; a.K = 64; a.nh = 16;
        gemm_bt<64, 64, 1><<<dim3(1, 16, 64), blk, 0, stream>>>(a);
    }
    cvt_bf16<<<4096, blk, 0, stream>>>(ffn_w1, w_f1, 8388608);
    cvt_bf16<<<2048, blk, 0, stream>>>(ffn_w2, w_f2, 4194304);

    softmax64<<<16384, blk, 0, stream>>>(Sbuf);
    {
        GArgs a{}; a.A = Sbuf; a.lda = 64; a.sAb = 1048576; a.sAh = 65536;
        a.B = vt; a.ldb = 64; a.sBb = 65536; a.sBh = 4096;
        a.C = Obuf; a.ldc = 1024; a.sCb = 1048576; a.sCh = 64;
        a.K = 64; a.nh = 16; a.scale = 1.f;
        gemm_bt<64, 64, 0><<<dim3(1, 16, 64), blk, 0, stream>>>(a);
    }
    {
        GArgs a{}; a.A = Obuf; a.lda = 1024; a.B = w_cawo; a.ldb = 1024;
        a.ldc = 1024; a.bias = ca_bo; a.resid = resid; a.gate = gate;
        a.scale = 1.f; a.K = 1024; a.nh = 1;
        gemm_bt<128, 128, 2><<<dim3(8, 32, 1), blk, 0, stream>>>(a);
    }

    ln_rows<<<4096, blk, 0, stream>>>(resid, ffn_g, ffn_b, lnbuf);
    for (int rc = 0; rc < 2; rc++) {
        const long ro = (long)rc * 2048;
        {
            GArgs a{}; a.A = lnbuf + ro * 1024; a.lda = 1024; a.B = w_f1; a.ldb = 1024;
            a.C = f1; a.ldc = 8192; a.bias = ffn_b1; a.K = 1024; a.nh = 1; a.scale = 1.f;
            gemm_bt<128, 128, 0><<<dim3(64, 16, 1), blk, 0, stream>>>(a);
        }
        geglu_inplace<<<4096, blk, 0, stream>>>(f1);
        {
            GArgs a{}; a.A = f1; a.lda = 8192; a.B = w_f2; a.ldb = 4096;
            a.ldc = 1024; a.bias = ffn_b2; a.resid = resid + ro * 1024; a.outf = out + ro * 1024;
            a.scale = 1.f; a.K = 4096; a.nh = 1;
            gemm_bt<128, 64, 3><<<dim3(8, 16, 1), blk, 0, stream>>>(a);
        }
    }
}

// Round 6
// 898.584 us; speedup vs baseline: 1.0351x; 1.0351x over previous
//
#include <hip/hip_runtime.h>
#include <hip/hip_bf16.h>
#include <cstdint>

// Problem constants: B=4, L=1024, D=1024, H=16, HD=64, FF=4096, NS=64
// Inputs: fp32 (per reference setup_inputs). Output: fp32 (reference returns float32).
#define DEVI __device__ __forceinline__

typedef __attribute__((ext_vector_type(8))) short  short8;
typedef __attribute__((ext_vector_type(8))) __bf16 bf16x8;
typedef __attribute__((ext_vector_type(4))) float  f32x4;

DEVI float bf2f(short s) {
    unsigned u = ((unsigned)(unsigned short)s) << 16;
    return __builtin_bit_cast(float, u);
}
DEVI short f2bf(float f) {
    unsigned u = __builtin_bit_cast(unsigned, f);
    u = u + 0x7FFF + ((u >> 16) & 1);   // RNE
    return (short)(u >> 16);
}

#define GLDS(gp, lp) __builtin_amdgcn_global_load_lds( \
    (const __attribute__((address_space(1))) void*)(gp), \
    (__attribute__((address_space(3))) void*)(lp), 16, 0, 0)

// ---------------------------------------------------- fp32 -> bf16 convert
__global__ __launch_bounds__(256) void cvt_bf16(const float* src, short* dst, long n) {
    const long i = ((long)blockIdx.x * 256 + threadIdx.x) * 8;
    const float4 a = *(const float4*)&src[i];
    const float4 b = *(const float4*)&src[i + 4];
    short8 o;
    o[0] = f2bf(a.x); o[1] = f2bf(a.y); o[2] = f2bf(a.z); o[3] = f2bf(a.w);
    o[4] = f2bf(b.x); o[5] = f2bf(b.y); o[6] = f2bf(b.z); o[7] = f2bf(b.w);
    *(short8*)&dst[i] = o;
}

// All weight conversions in one launch. blkStart is a prefix-sum of per-segment blocks.
struct CvtArgs {
    const float* src[6]; short* dst[6]; int blkStart[7];
};
__global__ __launch_bounds__(256) void cvt_all(CvtArgs c) {
    const int b = blockIdx.x;
    int s = 0;
    while (b >= c.blkStart[s + 1]) s++;
    const long i = ((long)(b - c.blkStart[s]) * 256 + threadIdx.x) * 8;
    const float4 a0 = *(const float4*)&c.src[s][i];
    const float4 a1 = *(const float4*)&c.src[s][i + 4];
    short8 o;
    o[0] = f2bf(a0.x); o[1] = f2bf(a0.y); o[2] = f2bf(a0.z); o[3] = f2bf(a0.w);
    o[4] = f2bf(a1.x); o[5] = f2bf(a1.y); o[6] = f2bf(a1.z); o[7] = f2bf(a1.w);
    *(short8*)&c.dst[s][i] = o;
}

// ---------------------------------------------------------------- GEMM (NT)
// C[m,n] = sum_k A[m,k] * B[n,k]  -- A,B bf16 K-contiguous, fp32 accum.
// 2-phase double-buffered pipeline: issue stage(t+1) -> compute(t) -> vmcnt(0)+barrier.
struct GArgs {
    const short* A; long lda, sAb, sAh;
    const short* B; long ldb, sBb, sBh;
    short* C;       long ldc, sCb, sCh;
    const float* bias;                       // len-N fp32, nullable
    const float* addm; long ldad, sDb, sDh;  // additive fp32 matrix (alibi), nullable
    float* resid;                            // fp32 residual, uses ldc
    float* outf;                             // EPI3 fp32 output
    const float* gate;                       // fp32 scalar, nullable
    const float* addf;                       // EPI2: fp32 base matrix (else resid is base)
    float scale;
    int K, nh;
};

// EPI: 0: C=bf16(acc+bias)  [LDS-packed coalesced store]
//      1: C=bf16(acc*scale + addm)
//      2: resid = (addf?addf:resid) + gatescale*(acc+bias)   (gatescale = scale*sigmoid(*gate))
//      3: outf = fp32(resid + acc + bias)
template<int BM, int BN, int EPI>
__global__ __launch_bounds__(256) void gemm_bt(GArgs a) {
    constexpr int WM = BM / 2, WN = BN / 2, MI = WM / 16, NI = WN / 16;
    __shared__ __align__(16) short As[2][BM * 32];
    __shared__ __align__(16) short Bs[2][BN * 32];
    const int tid = threadIdx.x;
    const int wave = tid >> 6, lane = tid & 63;
    const int wm = (wave >> 1) * WM, wn = (wave & 1) * WN;
    const int q = lane >> 4, r = lane & 15;
    // XCD-aware bijective swizzle over (x,y); requires gx*gy % 8 == 0 (all call sites comply)
    const int gx = gridDim.x, gy = gridDim.y;
    int flat = (int)(blockIdx.y * gx + blockIdx.x);
    { const int cp = (gx * gy) >> 3; flat = (flat & 7) * cp + (flat >> 3); }
    const int bx = flat % gx, by = flat / gx;
    const long bb = blockIdx.z / a.nh, hh = blockIdx.z % a.nh;
    const short* Ab = a.A + bb * a.sAb + hh * a.sAh + (long)by * BM * a.lda;
    const short* Bb = a.B + bb * a.sBb + hh * a.sBh + (long)bx * BN * a.ldb;
    const int trow = tid >> 2;            // 4 threads/row, 8 bf16 (16B) each
    const int tcol = (tid & 3) * 8;
    f32x4 acc[MI][NI] = {};
    const int nt = a.K >> 5;

    auto stage = [&](int buf, int k0) {
#pragma unroll
        for (int i = 0; i < BM / 64; i++)
            GLDS(Ab + (long)(i * 64 + trow) * a.lda + k0 + tcol,
                 &As[buf][(i * 64 + trow) * 32 + tcol]);
#pragma unroll
        for (int i = 0; i < BN / 64; i++)
            GLDS(Bb + (long)(i * 64 + trow) * a.ldb + k0 + tcol,
                 &Bs[buf][(i * 64 + trow) * 32 + tcol]);
    };

    // prologue
    stage(0, 0);
    asm volatile("s_waitcnt vmcnt(0)" ::: "memory");
    __builtin_amdgcn_s_barrier();

    int cur = 0;
    for (int t = 0; t < nt; ++t) {
        if (t + 1 < nt) stage(cur ^ 1, (t + 1) << 5);
        bf16x8 av[MI], bv[NI];
#pragma unroll
        for (int mi = 0; mi < MI; mi++)
            av[mi] = __builtin_bit_cast(bf16x8, *(const short8*)&As[cur][(wm + mi * 16 + r) * 32 + q * 8]);
#pragma unroll
        for (int ni = 0; ni < NI; ni++)
            bv[ni] = __builtin_bit_cast(bf16x8, *(const short8*)&Bs[cur][(wn + ni * 16 + r) * 32 + q * 8]);
#pragma unroll
        for (int mi = 0; mi < MI; mi++)
#pragma unroll
            for (int ni = 0; ni < NI; ni++)
                acc[mi][ni] = __builtin_amdgcn_mfma_f32_16x16x32_bf16(av[mi], bv[ni], acc[mi][ni], 0, 0, 0);
        asm volatile("s_waitcnt vmcnt(0) lgkmcnt(0)" ::: "memory");
        __builtin_amdgcn_s_barrier();
        cur ^= 1;
    }

    const long m0 = (long)by * BM + wm;
    const long n0 = (long)bx * BN + wn;
    if constexpr (EPI == 0) {
        // LDS-packed coalesced bf16 store. Per-wave scratch 16 x (WN+2) shorts, staged
        // per mi-group (16 rows), read back as short8 -> 128B-run global stores.
        short* scrbase = &As[0][0];           // As[2] contiguous: 2*BM*32 shorts >= 4*16*(WN+2)
        short* scr = scrbase + wave * 16 * (WN + 2);
        short* Cbase = a.C + bb * a.sCb + hh * a.sCh;
        constexpr int LPR = WN / 8;           // lanes per row in store pass
        constexpr int RPI = 64 / LPR;         // rows per store instruction
        const int srow = lane / LPR, scol = (lane % LPR) * 8;
#pragma unroll
        for (int mi = 0; mi < MI; mi++) {
            asm volatile("s_waitcnt lgkmcnt(0)" ::: "memory");
#pragma unroll
            for (int ni = 0; ni < NI; ni++)
#pragma unroll
                for (int j = 0; j < 4; j++) {
                    float v = acc[mi][ni][j];
                    if (a.bias) v += a.bias[n0 + ni * 16 + r];
                    scr[(q * 4 + j) * (WN + 2) + ni * 16 + r] = f2bf(v);
                }
            asm volatile("s_waitcnt lgkmcnt(0)" ::: "memory");
#pragma unroll
            for (int it = 0; it < 16 / RPI; it++) {
                const int row = it * RPI + srow;
                const short8 vv = *(const short8*)&scr[row * (WN + 2) + scol];
                *(short8*)&Cbase[(m0 + mi * 16 + row) * a.ldc + n0 + scol] = vv;
            }
        }
        return;
    }
    float gs = a.scale;
    if (EPI == 2 && a.gate) gs *= 1.f / (1.f + __expf(-(*a.gate)));
#pragma unroll
    for (int mi = 0; mi < MI; mi++)
#pragma unroll
        for (int ni = 0; ni < NI; ni++)
#pragma unroll
            for (int j = 0; j < 4; j++) {
                const long m = m0 + mi * 16 + q * 4 + j;   // row = quad*4+reg
                const long n = n0 + ni * 16 + r;           // col = lane&15
                float v = acc[mi][ni][j];
                if constexpr (EPI == 1) {
                    v *= a.scale;
                    if (a.addm) v += a.addm[bb * a.sDb + hh * a.sDh + m * a.ldad + n];
                    a.C[bb * a.sCb + hh * a.sCh + m * a.ldc + n] = f2bf(v);
                } else if constexpr (EPI == 2) {
                    if (a.bias) v += a.bias[n];
                    const long idx = m * a.ldc + n;
                    const float base = a.addf ? a.addf[idx] : a.resid[idx];
                    a.resid[idx] = base + gs * v;
                } else if constexpr (EPI == 3) {
                    if (a.bias) v += a.bias[n];
                    a.outf[m * a.ldc + n] = a.resid[m * a.ldc + n] + v;
                }
            }
}

// ------------------------------------------------- fused GEMM + GeGLU (2-phase dbuf)
// C[m,n] = bf16( (A·Bv^T + b1[n]) * gelu(A·Bg^T + b1[4096+n]) )
struct GGArgs {
    const short* A; long lda;
    const short* Bv; const short* Bg; long ldb;
    short* C; long ldc;
    const float* b1;     // len 8192
    int K;
};
__global__ __launch_bounds__(256) void gemm_geglu(GGArgs a) {
    constexpr int BM = 128, BN = 64, WM = 64, WN = 32, MI = 4, NI = 2;
    __shared__ __align__(16) short As[2][BM * 32];
    __shared__ __align__(16) short Bs[2][BN * 32];
    __shared__ __align__(16) short Gs[2][BN * 32];
    const int tid = threadIdx.x;
    const int wave = tid >> 6, lane = tid & 63;
    const int wm = (wave >> 1) * WM, wn = (wave & 1) * WN;
    const int q = lane >> 4, r = lane & 15;
    const int gx = gridDim.x, gy = gridDim.y;
    int flat = (int)(blockIdx.y * gx + blockIdx.x);
    { const int cp = (gx * gy) >> 3; flat = (flat & 7) * cp + (flat >> 3); }
    const int bx = flat % gx, by = flat / gx;
    const short* Ab = a.A + (long)by * BM * a.lda;
    const short* Bb = a.Bv + (long)bx * BN * a.ldb;
    const short* Gb = a.Bg + (long)bx * BN * a.ldb;
    const int trow = tid >> 2, tcol = (tid & 3) * 8;
    f32x4 accv[MI][NI] = {}, accg[MI][NI] = {};
    const int nt = a.K >> 5;

    auto stage = [&](int buf, int k0) {
#pragma unroll
        for (int i = 0; i < 2; i++)
            GLDS(Ab + (long)(i * 64 + trow) * a.lda + k0 + tcol,
                 &As[buf][(i * 64 + trow) * 32 + tcol]);
        GLDS(Bb + (long)trow * a.ldb + k0 + tcol, &Bs[buf][trow * 32 + tcol]);
        GLDS(Gb + (long)trow * a.ldb + k0 + tcol, &Gs[buf][trow * 32 + tcol]);
    };

    stage(0, 0);
    asm volatile("s_waitcnt vmcnt(0)" ::: "memory");
    __builtin_amdgcn_s_barrier();

    int cur = 0;
    for (int t = 0; t < nt; ++t) {
        if (t + 1 < nt) stage(cur ^ 1, (t + 1) << 5);
        bf16x8 av[MI], bv[NI], gv[NI];
#pragma unroll
        for (int mi = 0; mi < MI; mi++)
            av[mi] = __builtin_bit_cast(bf16x8, *(const short8*)&As[cur][(wm + mi * 16 + r) * 32 + q * 8]);
#pragma unroll
        for (int ni = 0; ni < NI; ni++) {
            bv[ni] = __builtin_bit_cast(bf16x8, *(const short8*)&Bs[cur][(wn + ni * 16 + r) * 32 + q * 8]);
            gv[ni] = __builtin_bit_cast(bf16x8, *(const short8*)&Gs[cur][(wn + ni * 16 + r) * 32 + q * 8]);
        }
#pragma unroll
        for (int mi = 0; mi < MI; mi++)
#pragma unroll
            for (int ni = 0; ni < NI; ni++) {
                accv[mi][ni] = __builtin_amdgcn_mfma_f32_16x16x32_bf16(av[mi], bv[ni], accv[mi][ni], 0, 0, 0);
                accg[mi][ni] = __builtin_amdgcn_mfma_f32_16x16x32_bf16(av[mi], gv[ni], accg[mi][ni], 0, 0, 0);
            }
        asm volatile("s_waitcnt vmcnt(0) lgkmcnt(0)" ::: "memory");
        __builtin_amdgcn_s_barrier();
        cur ^= 1;
    }

    const long m0 = (long)by * BM + wm;
    const long n0 = (long)bx * BN + wn;
    // LDS-packed coalesced store (WN=32: 4 lanes/row, 16 rows/instr, 1 iter per mi)
    short* scr = &As[0][0] + wave * 16 * (WN + 2);
    const int srow = lane >> 2, scol = (lane & 3) * 8;
#pragma unroll
    for (int mi = 0; mi < MI; mi++) {
        asm volatile("s_waitcnt lgkmcnt(0)" ::: "memory");
#pragma unroll
        for (int ni = 0; ni < NI; ni++)
#pragma unroll
            for (int j = 0; j < 4; j++) {
                const long n = n0 + ni * 16 + r;
                const float v = accv[mi][ni][j] + a.b1[n];
                const float g = accg[mi][ni][j] + a.b1[4096 + n];
                const float ge = 0.5f * g * (1.f + erff(g * 0.7071067811865476f));
                scr[(q * 4 + j) * (WN + 2) + ni * 16 + r] = f2bf(v * ge);
            }
        asm volatile("s_waitcnt lgkmcnt(0)" ::: "memory");
        const short8 vv = *(const short8*)&scr[srow * (WN + 2) + scol];
        *(short8*)&a.C[(m0 + mi * 16 + srow) * a.ldc + n0 + scol] = vv;
    }
}

// ------------------------------------------------- flash self-attention
// grid: (16 q-tiles, 64 bh). Block 256 = 4 waves; wave w owns rows [w*16,w*16+16).
// Q hoisted to registers (Q LDS tile reused as P buffer); K/V double-buffered.
// Per iteration: issue alibi(kt) + stage(kt+1), compute on buf[cur], vmcnt(0)+barrier.
__global__ __launch_bounds__(256) void flash_sa(const short* qkv, const short* vt,
                                                const float* alibi, short* Obuf) {
    __shared__ __align__(16) short Ps[64 * 64];          // Q staging, then P tiles, then O pack
    __shared__ __align__(16) short Ks[2][64 * 64], Vs[2][64 * 64];
    const int tid = threadIdx.x;
    const int wave = tid >> 6, lane = tid & 63, q = lane >> 4, r = lane & 15;
    int flat = (int)(blockIdx.y * 16 + blockIdx.x);     // nwg = 1024
    flat = (flat & 7) * 128 + (flat >> 3);              // XCD chunk swizzle
    const int qt = flat & 15, bh = flat >> 4, b = bh >> 4, h = bh & 15;
    const long qrow0 = (long)b * 1024 + qt * 64;
    const int rw = tid >> 3, sp = tid & 7;   // loader: 8 threads/row, 16B each

    auto stage_kv = [&](int buf, int kt) {
#pragma unroll
        for (int i = 0; i < 2; i++) {
            const int row = i * 32 + rw;
            const int c8 = (sp ^ (row & 7)) * 8;
            GLDS(qkv + ((long)b * 1024 + kt * 64 + row) * 3072 + 1024 + h * 64 + c8,
                 &Ks[buf][row * 64 + sp * 8]);
            GLDS(vt + ((long)bh * 64 + row) * 1024 + kt * 64 + c8,
                 &Vs[buf][row * 64 + sp * 8]);
        }
    };

    // stage Q (into Ps) + K/V tile 0
#pragma unroll
    for (int i = 0; i < 2; i++) {
        const int row = i * 32 + rw;
        const int c8 = (sp ^ (row & 7)) * 8;
        GLDS(qkv + (qrow0 + row) * 3072 + h * 64 + c8, &Ps[row * 64 + sp * 8]);
    }
    stage_kv(0, 0);
    asm volatile("s_waitcnt vmcnt(0)" ::: "memory");
    __builtin_amdgcn_s_barrier();

    // Q-hoist: each wave reads only its own 16-row strip (rows wave*16 + r)
    const int arow = wave * 16 + r;
    bf16x8 qv[2];
#pragma unroll
    for (int kk = 0; kk < 2; kk++)
        qv[kk] = __builtin_bit_cast(bf16x8,
            *(const short8*)&Ps[arow * 64 + (((kk * 4 + q) ^ (arow & 7)) * 8)]);
    // (no barrier: each wave overwrites only its own strip of Ps below)

    f32x4 o[4] = {};            // O accum: row q*4+j, col d = nd*16+r
    float m_run[4], l_run[4];
#pragma unroll
    for (int j = 0; j < 4; j++) { m_run[j] = -1e30f; l_run[j] = 0.f; }

    int cur = 0;
    for (int kt = 0; kt < 16; kt++) {
        // alibi loads for kt (issued before stage so its auto-wait leaves stage in flight)
        float al[4][4];
        const float* ab = alibi + (long)bh * 1048576 + (long)(qt * 64 + wave * 16) * 1024 + kt * 64;
#pragma unroll
        for (int ni = 0; ni < 4; ni++)
#pragma unroll
            for (int j = 0; j < 4; j++)
                al[ni][j] = ab[(q * 4 + j) * 1024 + ni * 16 + r];
        if (kt < 15) stage_kv(cur ^ 1, kt + 1);

        // S = Q K^T  (wave strip: 16 rows x 64 cols) from Ks[cur]
        f32x4 sacc[4] = {};
        __builtin_amdgcn_s_setprio(1);
#pragma unroll
        for (int kk = 0; kk < 2; kk++) {
#pragma unroll
            for (int ni = 0; ni < 4; ni++) {
                const int brow = ni * 16 + r;
                const bf16x8 bv = __builtin_bit_cast(bf16x8,
                    *(const short8*)&Ks[cur][brow * 64 + (((kk * 4 + q) ^ (brow & 7)) * 8)]);
                sacc[ni] = __builtin_amdgcn_mfma_f32_16x16x32_bf16(qv[kk], bv, sacc[ni], 0, 0, 0);
            }
        }
        __builtin_amdgcn_s_setprio(0);
        float s[4][4];
#pragma unroll
        for (int ni = 0; ni < 4; ni++)
#pragma unroll
            for (int j = 0; j < 4; j++)
                s[ni][j] = sacc[ni][j] * 0.125f + al[ni][j];

        // online softmax: row = q*4+j, owned by the 16 lanes sharing q
        float p[4][4];
#pragma unroll
        for (int j = 0; j < 4; j++) {
            float mx = fmaxf(fmaxf(s[0][j], s[1][j]), fmaxf(s[2][j], s[3][j]));
#pragma unroll
            for (int off = 8; off; off >>= 1) mx = fmaxf(mx, __shfl_xor(mx, off));
            const float newm = fmaxf(m_run[j], mx);
            const float sc = __expf(m_run[j] - newm);
            m_run[j] = newm;
            float rs = 0.f;
#pragma unroll
            for (int ni = 0; ni < 4; ni++) { p[ni][j] = __expf(s[ni][j] - newm); rs += p[ni][j]; }
#pragma unroll
            for (int off = 8; off; off >>= 1) rs += __shfl_xor(rs, off);
            l_run[j] = l_run[j] * sc + rs;
#pragma unroll
            for (int nd = 0; nd < 4; nd++) o[nd][j] *= sc;
        }

        // P -> bf16 -> LDS (own strip only; swizzled elementwise)
#pragma unroll
        for (int ni = 0; ni < 4; ni++)
#pragma unroll
            for (int j = 0; j < 4; j++) {
                const int row = wave * 16 + q * 4 + j;
                const int col = ni * 16 + r;
                const int scol = (((col >> 3) ^ (row & 7)) << 3) | (col & 7);
                Ps[row * 64 + scol] = f2bf(p[ni][j]);
            }
        asm volatile("s_waitcnt lgkmcnt(0)" ::: "memory");   // within-wave write->read

        // O += P @ V from Vs[cur]
        const int prow = wave * 16 + r;
        __builtin_amdgcn_s_setprio(1);
#pragma unroll
        for (int kk = 0; kk < 2; kk++) {
            const bf16x8 pa = __builtin_bit_cast(bf16x8,
                *(const short8*)&Ps[prow * 64 + (((kk * 4 + q) ^ (prow & 7)) * 8)]);
#pragma unroll
            for (int nd = 0; nd < 4; nd++) {
                const int vrow = nd * 16 + r;
                const bf16x8 vv = __builtin_bit_cast(bf16x8,
                    *(const short8*)&Vs[cur][vrow * 64 + (((kk * 4 + q) ^ (vrow & 7)) * 8)]);
                o[nd] = __builtin_amdgcn_mfma_f32_16x16x32_bf16(pa, vv, o[nd], 0, 0, 0);
            }
        }
        __builtin_amdgcn_s_setprio(0);
        asm volatile("s_waitcnt vmcnt(0) lgkmcnt(0)" ::: "memory");
        __builtin_amdgcn_s_barrier();
        cur ^= 1;
    }

    // epilogue: O /= l, LDS-pack (own Ps strip), coalesced 16B stores
    short* scr = &Ps[wave * 1024];           // 16 rows x 64 cols, stride 64
#pragma unroll
    for (int j = 0; j < 4; j++) {
        const float li = 1.f / l_run[j];
#pragma unroll
        for (int nd = 0; nd < 4; nd++)
            scr[(q * 4 + j) * 64 + nd * 16 + r] = f2bf(o[nd][j] * li);
    }
    asm volatile("s_waitcnt lgkmcnt(0)" ::: "memory");
    const int srow = lane >> 3, scol = (lane & 7) * 8;
#pragma unroll
    for (int it = 0; it < 2; it++) {
        const int row = it * 8 + srow;
        const short8 vv = *(const short8*)&scr[row * 64 + scol];
        *(short8*)&Obuf[(qrow0 + wave * 16 + row) * 1024 + h * 64 + scol] = vv;
    }
}

// ------------------------------------------------- flash cross-attention
// Single KV tile (NS=64): S = Q2 K2^T / 8, softmax, O = P V2. grid (16, 64).
__global__ __launch_bounds__(256) void flash_ca(const short* q2, const short* kv2,
                                                const short* vt, short* Obuf) {
    __shared__ __align__(16) short Qs[64 * 64], Ks[64 * 64], Vs[64 * 64], Ps[64 * 64];
    const int tid = threadIdx.x;
    const int wave = tid >> 6, lane = tid & 63, q = lane >> 4, r = lane & 15;
    int flat = (int)(blockIdx.y * 16 + blockIdx.x);
    flat = (flat & 7) * 128 + (flat >> 3);
    const int qt = flat & 15, bh = flat >> 4, b = bh >> 4, h = bh & 15;
    const long qrow0 = (long)b * 1024 + qt * 64;
    const int rw = tid >> 3, sp = tid & 7;

#pragma unroll
    for (int i = 0; i < 2; i++) {
        const int row = i * 32 + rw;
        const int c8 = (sp ^ (row & 7)) * 8;
        GLDS(q2 + (qrow0 + row) * 1024 + h * 64 + c8, &Qs[row * 64 + sp * 8]);
        GLDS(kv2 + ((long)b * 64 + row) * 2048 + h * 64 + c8, &Ks[row * 64 + sp * 8]);
        GLDS(vt + ((long)bh * 64 + row) * 64 + c8, &Vs[row * 64 + sp * 8]);
    }
    asm volatile("s_waitcnt vmcnt(0)" ::: "memory");
    __syncthreads();

    // S = Q K^T / 8
    f32x4 sacc[4] = {};
    const int arow = wave * 16 + r;
    __builtin_amdgcn_s_setprio(1);
#pragma unroll
    for (int kk = 0; kk < 2; kk++) {
        const bf16x8 av = __builtin_bit_cast(bf16x8,
            *(const short8*)&Qs[arow * 64 + (((kk * 4 + q) ^ (arow & 7)) * 8)]);
#pragma unroll
        for (int ni = 0; ni < 4; ni++) {
            const int brow = ni * 16 + r;
            const bf16x8 bv = __builtin_bit_cast(bf16x8,
                *(const short8*)&Ks[brow * 64 + (((kk * 4 + q) ^ (brow & 7)) * 8)]);
            sacc[ni] = __builtin_amdgcn_mfma_f32_16x16x32_bf16(av, bv, sacc[ni], 0, 0, 0);
        }
    }
    __builtin_amdgcn_s_setprio(0);
    // softmax over the full 64 keys
    float p[4][4], linv[4];
#pragma unroll
    for (int j = 0; j < 4; j++) {
        float s0 = sacc[0][j] * 0.125f, s1 = sacc[1][j] * 0.125f;
        float s2 = sacc[2][j] * 0.125f, s3 = sacc[3][j] * 0.125f;
        float mx = fmaxf(fmaxf(s0, s1), fmaxf(s2, s3));
#pragma unroll
        for (int off = 8; off; off >>= 1) mx = fmaxf(mx, __shfl_xor(mx, off));
        p[0][j] = __expf(s0 - mx); p[1][j] = __expf(s1 - mx);
        p[2][j] = __expf(s2 - mx); p[3][j] = __expf(s3 - mx);
        float rs = p[0][j] + p[1][j] + p[2][j] + p[3][j];
#pragma unroll
        for (int off = 8; off; off >>= 1) rs += __shfl_xor(rs, off);
        linv[j] = 1.f / rs;
    }
#pragma unroll
    for (int ni = 0; ni < 4; ni++)
#pragma unroll
        for (int j = 0; j < 4; j++) {
            const int row = wave * 16 + q * 4 + j;
            const int col = ni * 16 + r;
            const int scol = (((col >> 3) ^ (row & 7)) << 3) | (col & 7);
            Ps[row * 64 + scol] = f2bf(p[ni][j]);
        }
    asm volatile("s_waitcnt lgkmcnt(0)" ::: "memory");

    f32x4 o[4] = {};
    const int prow = wave * 16 + r;
    __builtin_amdgcn_s_setprio(1);
#pragma unroll
    for (int kk = 0; kk < 2; kk++) {
        const bf16x8 pa = __builtin_bit_cast(bf16x8,
            *(const short8*)&Ps[prow * 64 + (((kk * 4 + q) ^ (prow & 7)) * 8)]);
#pragma unroll
        for (int nd = 0; nd < 4; nd++) {
            const int vrow = nd * 16 + r;
            const bf16x8 vv = __builtin_bit_cast(bf16x8,
                *(const short8*)&Vs[vrow * 64 + (((kk * 4 + q) ^ (vrow & 7)) * 8)]);
            o[nd] = __builtin_amdgcn_mfma_f32_16x16x32_bf16(pa, vv, o[nd], 0, 0, 0);
        }
    }
    __builtin_amdgcn_s_setprio(0);

    // LDS-packed coalesced O store (own Ps strip; PV reads of own strip are done)
    short* scr = &Ps[wave * 1024];
#pragma unroll
    for (int j = 0; j < 4; j++)
#pragma unroll
        for (int nd = 0; nd < 4; nd++)
            scr[(q * 4 + j) * 64 + nd * 16 + r] = f2bf(o[nd][j] * linv[j]);
    asm volatile("s_waitcnt lgkmcnt(0)" ::: "memory");
    const int srow = lane >> 3, scol = (lane & 7) * 8;
#pragma unroll
    for (int it = 0; it < 2; it++) {
        const int row = it * 8 + srow;
        const short8 vv = *(const short8*)&scr[row * 64 + scol];
        *(short8*)&Obuf[(qrow0 + wave * 16 + row) * 1024 + h * 64 + scol] = vv;
    }
}

// ------------------------------------------------------------- LayerNorm
__global__ __launch_bounds__(256) void ln_rows(const float* X, const float* gw,
                                               const float* bw, short* Y) {
    const long row = blockIdx.x;
    const float* x = X + row * 1024;
    const int t = threadIdx.x;
    float v[4], s1 = 0.f, s2 = 0.f;
#pragma unroll
    for (int i = 0; i < 4; i++) {
        v[i] = x[t + i * 256];
        s1 += v[i]; s2 += v[i] * v[i];
    }
#pragma unroll
    for (int o = 32; o; o >>= 1) { s1 += __shfl_xor(s1, o); s2 += __shfl_xor(s2, o); }
    __shared__ float sm[8];
    if ((t & 63) == 0) { sm[t >> 6] = s1; sm[4 + (t >> 6)] = s2; }
    __syncthreads();
    s1 = sm[0] + sm[1] + sm[2] + sm[3];
    s2 = sm[4] + sm[5] + sm[6] + sm[7];
    const float mu = s1 * (1.f / 1024.f);
    const float var = s2 * (1.f / 1024.f) - mu * mu;
    const float rr = rsqrtf(var + 1e-5f);
#pragma unroll
    for (int i = 0; i < 4; i++) {
        const int c = t + i * 256;
        Y[row * 1024 + c] = f2bf((v[i] - mu) * rr * gw[c] + bw[c]);
    }
}

// ------------------------------------------------------------- Softmax (fallback path)
__global__ __launch_bounds__(256) void softmax1024(short* S) {
    const long row = blockIdx.x;
    short* p = S + row * 1024;
    const int t = threadIdx.x;
    float v[4];
#pragma unroll
    for (int i = 0; i < 4; i++) v[i] = bf2f(p[t + i * 256]);
    float m = fmaxf(fmaxf(v[0], v[1]), fmaxf(v[2], v[3]));
#pragma unroll
    for (int o = 32; o; o >>= 1) m = fmaxf(m, __shfl_xor(m, o));
    __shared__ float sm[4];
    if ((t & 63) == 0) sm[t >> 6] = m;
    __syncthreads();
    m = fmaxf(fmaxf(sm[0], sm[1]), fmaxf(sm[2], sm[3]));
    float e[4], s = 0.f;
#pragma unroll
    for (int i = 0; i < 4; i++) { e[i] = __expf(v[i] - m); s += e[i]; }
#pragma unroll
    for (int o = 32; o; o >>= 1) s += __shfl_xor(s, o);
    __syncthreads();
    if ((t & 63) == 0) sm[t >> 6] = s;
    __syncthreads();
    s = sm[0] + sm[1] + sm[2] + sm[3];
    const float inv = 1.f / s;
#pragma unroll
    for (int i = 0; i < 4; i++) p[t + i * 256] = f2bf(e[i] * inv);
}

__global__ __launch_bounds__(256) void softmax64(short* S) {
    const long row = (long)blockIdx.x * 4 + (threadIdx.x >> 6);
    const int lane = threadIdx.x & 63;
    short* p = S + row * 64;
    float v = bf2f(p[lane]);
    float m = v;
#pragma unroll
    for (int o = 32; o; o >>= 1) m = fmaxf(m, __shfl_xor(m, o));
    float e = __expf(v - m), s = e;
#pragma unroll
    for (int o = 32; o; o >>= 1) s += __shfl_xor(s, o);
    p[lane] = f2bf(e / s);
}

// ----------------------------------------------------- V transposes (per head)
__global__ __launch_bounds__(256) void transpose_v_sa(const short* qkv, short* vt) {
    __shared__ short tbuf[64][68];
    const int j0 = blockIdx.x * 64, h = blockIdx.y, b = blockIdx.z;
    const int tid = threadIdx.x;
#pragma unroll
    for (int i = 0; i < 16; i++) {
        const int idx = i * 256 + tid, jj = idx >> 6, hd = idx & 63;
        tbuf[jj][hd] = qkv[(long)(b * 1024 + j0 + jj) * 3072 + 2048 + h * 64 + hd];
    }
    __syncthreads();
    const long bh = b * 16 + h;
#pragma unroll
    for (int i = 0; i < 16; i++) {
        const int idx = i * 256 + tid, hd = idx >> 6, jj = idx & 63;
        vt[(bh * 64 + hd) * 1024 + j0 + jj] = tbuf[jj][hd];
    }
}

__global__ __launch_bounds__(256) void transpose_v_ca(const short* kv2, short* vt2) {
    __shared__ short tbuf[64][68];
    const int bh = blockIdx.x, b = bh >> 4, h = bh & 15;
    const int tid = threadIdx.x;
#pragma unroll
    for (int i = 0; i < 16; i++) {
        const int idx = i * 256 + tid, jj = idx >> 6, hd = idx & 63;
        tbuf[jj][hd] = kv2[(long)(b * 64 + jj) * 2048 + 1024 + h * 64 + hd];
    }
    __syncthreads();
#pragma unroll
    for (int i = 0; i < 16; i++) {
        const int idx = i * 256 + tid, hd = idx >> 6, jj = idx & 63;
        vt2[((long)bh * 64 + hd) * 64 + jj] = tbuf[jj][hd];
    }
}

// ------------------------------------------------------------- elementwise (fallback)
__global__ __launch_bounds__(256) void geglu_inplace(short* f1) {
    const long i = (long)blockIdx.x * 256 + threadIdx.x;  // 8 elems each
    const long m = i >> 9, j8 = (i & 511) * 8;
    const short8 av = *(const short8*)&f1[m * 8192 + j8];
    const short8 gv = *(const short8*)&f1[m * 8192 + 4096 + j8];
    short8 o;
#pragma unroll
    for (int jj = 0; jj < 8; jj++) {
        const float xv = bf2f(av[jj]), gg = bf2f(gv[jj]);
        const float ge = 0.5f * gg * (1.f + erff(gg * 0.7071067811865476f));
        o[jj] = f2bf(xv * ge);
    }
    *(short8*)&f1[m * 8192 + j8] = o;
}

// ---------------------------------------------------------------- launch
extern "C" void kernel_launch(void* const* d_in, const int* in_sizes, int n_in,
                              void* d_out, int out_size, void* d_ws, size_t ws_size,
                              hipStream_t stream) {
    const float* x        = (const float*)d_in[0];
    const float* alibi    = (const float*)d_in[1];
    const float* species  = (const float*)d_in[2];
    const float* n1g      = (const float*)d_in[3];
    const float* n1b      = (const float*)d_in[4];
    const float* sa_wqkv  = (const float*)d_in[5];
    const float* sa_bqkv  = (const float*)d_in[6];
    const float* sa_wo    = (const float*)d_in[7];
    const float* sa_bo    = (const float*)d_in[8];
    const float* ca_nq_g  = (const float*)d_in[9];
    const float* ca_nq_b  = (const float*)d_in[10];
    const float* ca_nkv_g = (const float*)d_in[11];
    const float* ca_nkv_b = (const float*)d_in[12];
    const float* ca_wqkv  = (const float*)d_in[13];
    const float* ca_bqkv  = (const float*)d_in[14];
    const float* ca_wo    = (const float*)d_in[15];
    const float* ca_bo    = (const float*)d_in[16];
    const float* gate     = (const float*)d_in[17];
    const float* ffn_g    = (const float*)d_in[18];
    const float* ffn_b    = (const float*)d_in[19];
    const float* ffn_w1   = (const float*)d_in[20];
    const float* ffn_b1   = (const float*)d_in[21];
    const float* ffn_w2   = (const float*)d_in[22];
    const float* ffn_b2   = (const float*)d_in[23];
    float* out = (float*)d_out;   // fp32 output (reference returns float32)

    const dim3 blk(256);
    char* ws = (char*)d_ws;

    if (ws_size >= (304ull << 20)) {
        // ---------------- de-chunked path (needs 304 MiB workspace) ----------------
        float* resid  = (float*)(ws);                  // [0,16M)    fp32 residual
        short* lnbuf  = (short*)(ws + (16l << 20));    // [16,24M)   LN outputs (bf16)
        short* Obuf   = (short*)(ws + (24l << 20));    // [24,32M)   attn head outputs
        short* vt     = (short*)(ws + (32l << 20));    // [32,40M)   transposed V
        short* qkv    = (short*)(ws + (40l << 20));    // [40,64M)   qkv (4096x3072) / q2
        short* w_saq  = (short*)(ws + (64l << 20));    // [64,70M)
        short* w_sawo = (short*)(ws + (70l << 20));    // [70,72M)
        short* w_caq  = (short*)(ws + (72l << 20));    // [72,78M)
        short* w_cawo = (short*)(ws + (78l << 20));    // [78,80M)
        short* w_f1   = (short*)(ws + (80l << 20));    // [80,96M)
        short* w_f2   = (short*)(ws + (96l << 20));    // [96,104M)
        short* kv2    = (short*)(ws + (104l << 20));   // [104,105M) CA k/v proj (256x2048)
        short* g1     = (short*)(ws + (240l << 20));   // [240,272M) geglu'd f1 (4096x4096)

        // Convert all weights fp32 -> bf16 in one launch
        {
            CvtArgs c{};
            c.src[0] = sa_wqkv; c.dst[0] = w_saq;
            c.src[1] = sa_wo;   c.dst[1] = w_sawo;
            c.src[2] = ca_wqkv; c.dst[2] = w_caq;
            c.src[3] = ca_wo;   c.dst[3] = w_cawo;
            c.src[4] = ffn_w1;  c.dst[4] = w_f1;
            c.src[5] = ffn_w2;  c.dst[5] = w_f2;
            const int nb[6] = {1536, 512, 1536, 512, 4096, 2048};
            int acc = 0;
            for (int i = 0; i < 6; i++) { c.blkStart[i] = acc; acc += nb[i]; }
            c.blkStart[6] = acc;
            cvt_all<<<acc, blk, 0, stream>>>(c);
        }

        // h = LN(x)
        ln_rows<<<4096, blk, 0, stream>>>(x, n1g, n1b, lnbuf);

        // qkv = h @ sa_wqkv^T + b   (4096 x 3072)
        {
            GArgs a{}; a.A = lnbuf; a.lda = 1024; a.B = w_saq; a.ldb = 1024;
            a.C = qkv; a.ldc = 3072; a.bias = sa_bqkv; a.K = 1024; a.nh = 1; a.scale = 1.f;
            gemm_bt<128, 128, 0><<<dim3(24, 32, 1), blk, 0, stream>>>(a);
        }
        transpose_v_sa<<<dim3(16, 16, 4), blk, 0, stream>>>(qkv, vt);

        // fused flash self-attention
        flash_sa<<<dim3(16, 64), blk, 0, stream>>>(qkv, vt, alibi, Obuf);

        {   // resid = x + O @ sa_wo^T + bo   (residual copy folded in)
            GArgs a{}; a.A = Obuf; a.lda = 1024; a.B = w_sawo; a.ldb = 1024;
            a.ldc = 1024; a.bias = sa_bo; a.resid = resid; a.addf = x;
            a.scale = 1.f; a.K = 1024; a.nh = 1;
            gemm_bt<128, 64, 2><<<dim3(16, 32, 1), blk, 0, stream>>>(a);
        }

        // ---- cross attention ----
        ln_rows<<<4096, blk, 0, stream>>>(resid, ca_nq_g, ca_nq_b, lnbuf);
        {   // q2 = LN(x) @ ca_wqkv[0:1024]^T + b
            GArgs a{}; a.A = lnbuf; a.lda = 1024; a.B = w_caq; a.ldb = 1024;
            a.C = qkv; a.ldc = 1024; a.bias = ca_bqkv; a.K = 1024; a.nh = 1; a.scale = 1.f;
            gemm_bt<128, 64, 0><<<dim3(16, 32, 1), blk, 0, stream>>>(a);
        }
        ln_rows<<<256, blk, 0, stream>>>(species, ca_nkv_g, ca_nkv_b, lnbuf);
        {   // kv2 = LN(species) @ ca_wqkv[1024:3072]^T + b   (256 x 2048)
            GArgs a{}; a.A = lnbuf; a.lda = 1024; a.B = w_caq + 1024 * 1024; a.ldb = 1024;
            a.C = kv2; a.ldc = 2048; a.bias = ca_bqkv + 1024; a.K = 1024; a.nh = 1; a.scale = 1.f;
            gemm_bt<128, 128, 0><<<dim3(16, 2, 1), blk, 0, stream>>>(a);
        }
        transpose_v_ca<<<64, blk, 0, stream>>>(kv2, vt);

        // fused flash cross-attention
        flash_ca<<<dim3(16, 64), blk, 0, stream>>>(qkv, kv2, vt, Obuf);

        {   // resid += sigmoid(gate) * (O @ ca_wo^T + bo)
            GArgs a{}; a.A = Obuf; a.lda = 1024; a.B = w_cawo; a.ldb = 1024;
            a.ldc = 1024; a.bias = ca_bo; a.resid = resid; a.gate = gate;
            a.scale = 1.f; a.K = 1024; a.nh = 1;
            gemm_bt<128, 64, 2><<<dim3(16, 32, 1), blk, 0, stream>>>(a);
        }

        // ---- FFN (fused GEMM+GeGLU, then f2) ----
        ln_rows<<<4096, blk, 0, stream>>>(resid, ffn_g, ffn_b, lnbuf);
        {   // g1 = (LN @ w1v^T + b1v) * gelu(LN @ w1g^T + b1g)   (4096 x 4096)
            GGArgs a{}; a.A = lnbuf; a.lda = 1024;
            a.Bv = w_f1; a.Bg = w_f1 + (long)4096 * 1024; a.ldb = 1024;
            a.C = g1; a.ldc = 4096; a.b1 = ffn_b1; a.K = 1024;
            gemm_geglu<<<dim3(64, 32, 1), blk, 0, stream>>>(a);
        }
        {   // out = resid + g1 @ ffn_w2^T + b2
            GArgs a{}; a.A = g1; a.lda = 4096; a.B = w_f2; a.ldb = 4096;
            a.ldc = 1024; a.bias = ffn_b2; a.resid = resid; a.outf = out;
            a.scale = 1.f; a.K = 4096; a.nh = 1;
            gemm_bt<128, 64, 3><<<dim3(16, 32, 1), blk, 0, stream>>>(a);
        }
        return;
    }

    // ---------------- fallback: original 96 MiB chunked path ----------------
    float* resid  = (float*)(ws);                 // [0,16M)   fp32 residual
    short* lnbuf  = (short*)(ws + (16l << 20));   // [16,24M)  LN outputs (bf16)
    short* Obuf   = (short*)(ws + (24l << 20));   // [24,32M)  attn head outputs
    short* vt     = (short*)(ws + (32l << 20));   // [32,40M)  transposed V
    short* qkv    = (short*)(ws + (40l << 20));   // [40,64M)  qkv / q2+kv2; later FFN weights
    short* Sbuf   = (short*)(ws + (64l << 20));   // [64,96M)  scores / f1 chunks
    short* f1     = Sbuf;
    short* kv2    = qkv + 4194304;                // [48,49M)  CA k/v proj (256 x 2048)
    short* w_sawo = (short*)(ws + (80l << 20));   // [80,82M)  sa_wo bf16
    short* w_caq  = (short*)(ws + (82l << 20));   // [82,88M)  ca_wqkv bf16
    short* w_cawo = (short*)(ws + (88l << 20));   // [88,90M)  ca_wo bf16
    short* w_saq  = (short*)(ws + (90l << 20));   // [90,96M)  sa_wqkv bf16 (dead after qkv GEMM)
    short* w_f1   = qkv;                          // [40,56M)  ffn_w1 bf16 (after CA S2)
    short* w_f2   = (short*)(ws + (56l << 20));   // [56,64M)  ffn_w2 bf16

    cvt_bf16<<<1536, blk, 0, stream>>>(sa_wqkv, w_saq, 3145728);
    cvt_bf16<<<512,  blk, 0, stream>>>(sa_wo,   w_sawo, 1048576);
    cvt_bf16<<<1536, blk, 0, stream>>>(ca_wqkv, w_caq, 3145728);
    cvt_bf16<<<512,  blk, 0, stream>>>(ca_wo,   w_cawo, 1048576);

    hipMemcpyAsync(resid, x, (size_t)4194304 * 4, hipMemcpyDeviceToDevice, stream);
    ln_rows<<<4096, blk, 0, stream>>>(x, n1g, n1b, lnbuf);

    {
        GArgs a{}; a.A = lnbuf; a.lda = 1024; a.B = w_saq; a.ldb = 1024;
        a.C = qkv; a.ldc = 3072; a.bias = sa_bqkv; a.K = 1024; a.nh = 1; a.scale = 1.f;
        gemm_bt<128, 128, 0><<<dim3(24, 32, 1), blk, 0, stream>>>(a);
    }
    transpose_v_sa<<<dim3(16, 16, 4), blk, 0, stream>>>(qkv, vt);

    for (int c = 0; c < 8; c++) {
        const int b = c >> 1, hc = c & 1;
        const long boff = (long)b * 1024 * 3072;
        {
            GArgs a{}; a.A = qkv + boff + hc * 512; a.lda = 3072; a.sAh = 64;
            a.B = qkv + boff + 1024 + hc * 512; a.ldb = 3072; a.sBh = 64;
            a.C = Sbuf; a.ldc = 1024; a.sCh = 1048576;
            a.addm = alibi + ((long)(b * 16 + hc * 8)) * 1048576; a.ldad = 1024; a.sDh = 1048576;
            a.scale = 0.125f; a.K = 64; a.nh = 8;
            gemm_bt<128, 128, 1><<<dim3(8, 8, 8), blk, 0, stream>>>(a);
        }
        softmax1024<<<8192, blk, 0, stream>>>(Sbuf);
        {
            GArgs a{}; a.A = Sbuf; a.lda = 1024; a.sAh = 1048576;
            a.B = vt + (long)b * 1048576 + (long)hc * 8 * 65536; a.ldb = 1024; a.sBh = 65536;
            a.C = Obuf + (long)b * 1048576 + hc * 512; a.ldc = 1024; a.sCh = 64;
            a.K = 1024; a.nh = 8; a.scale = 1.f;
            gemm_bt<64, 64, 0><<<dim3(1, 16, 8), blk, 0, stream>>>(a);
        }
    }
    {
        GArgs a{}; a.A = Obuf; a.lda = 1024; a.B = w_sawo; a.ldb = 1024;
        a.ldc = 1024; a.bias = sa_bo; a.resid = resid; a.scale = 1.f; a.K = 1024; a.nh = 1;
        gemm_bt<128, 128, 2><<<dim3(8, 32, 1), blk, 0, stream>>>(a);
    }

    ln_rows<<<4096, blk, 0, stream>>>(resid, ca_nq_g, ca_nq_b, lnbuf);
    {
        GArgs a{}; a.A = lnbuf; a.lda = 1024; a.B = w_caq; a.ldb = 1024;
        a.C = qkv; a.ldc = 1024; a.bias = ca_bqkv; a.K = 1024; a.nh = 1; a.scale = 1.f;
        gemm_bt<128, 128, 0><<<dim3(8, 32, 1), blk, 0, stream>>>(a);
    }
    ln_rows<<<256, blk, 0, stream>>>(species, ca_nkv_g, ca_nkv_b, lnbuf);
    {
        GArgs a{}; a.A = lnbuf; a.lda = 1024; a.B = w_caq + 1024 * 1024; a.ldb = 1024;
        a.C = kv2; a.ldc = 2048; a.bias = ca_bqkv + 1024; a.K = 1024; a.nh = 1; a.scale = 1.f;
        gemm_bt<128, 128, 0><<<dim3(16, 2, 1), blk, 0, stream>>>(a);
    }
    transpose_v_ca<<<64, blk, 0, stream>>>(kv2, vt);
    {
        GArgs a{}; a.A = qkv; a.lda = 1024; a.sAb = 1048576; a.sAh = 64;
        a.B = kv2; a.ldb = 2048; a.sBb = 131072; a.sBh = 64;
        a.C = Sbuf; a.ldc = 64; a.sCb = 1048576; a.sCh = 65536;
        a.scale = 0.125f; a.K = 64; a.nh = 16;
        gemm_bt<64, 64, 1><<<dim3(1, 16, 64), blk, 0, stream>>>(a);
    }
    cvt_bf16<<<4096, blk, 0, stream>>>(ffn_w1, w_f1, 8388608);
    cvt_bf16<<<2048, blk, 0, stream>>>(ffn_w2, w_f2, 4194304);

    softmax64<<<16384, blk, 0, stream>>>(Sbuf);
    {
        GArgs a{}; a.A = Sbuf; a.lda = 64; a.sAb = 1048576; a.sAh = 65536;
        a.B = vt; a.ldb = 64; a.sBb = 65536; a.sBh = 4096;
        a.C = Obuf; a.ldc = 1024; a.sCb = 1048576; a.sCh = 64;
        a.K = 64; a.nh = 16; a.scale = 1.f;
        gemm_bt<64, 64, 0><<<dim3(1, 16, 64), blk, 0, stream>>>(a);
    }
    {
        GArgs a{}; a.A = Obuf; a.lda = 1024; a.B = w_cawo; a.ldb = 1024;
        a.ldc = 1024; a.bias = ca_bo; a.resid = resid; a.gate = gate;
        a.scale = 1.f; a.K = 1024; a.nh = 1;
        gemm_bt<128, 128, 2><<<dim3(8, 32, 1), blk, 0, stream>>>(a);
    }

    ln_rows<<<4096, blk, 0, stream>>>(resid, ffn_g, ffn_b, lnbuf);
    for (int rc = 0; rc < 2; rc++) {
        const long ro = (long)rc * 2048;
        {
            GArgs a{}; a.A = lnbuf + ro * 1024; a.lda = 1024; a.B = w_f1; a.ldb = 1024;
            a.C = f1; a.ldc = 8192; a.bias = ffn_b1; a.K = 1024; a.nh = 1; a.scale = 1.f;
            gemm_bt<128, 128, 0><<<dim3(64, 16, 1), blk, 0, stream>>>(a);
        }
        geglu_inplace<<<4096, blk, 0, stream>>>(f1);
        {
            GArgs a{}; a.A = f1; a.lda = 8192; a.B = w_f2; a.ldb = 4096;
            a.ldc = 1024; a.bias = ffn_b2; a.resid = resid + ro * 1024; a.outf = out + ro * 1024;
            a.scale = 1.f; a.K = 4096; a.nh = 1;
            gemm_bt<128, 64, 3><<<dim3(8, 16, 1), blk, 0, stream>>>(a);
        }
    }
}